// Round 3
// baseline (922.237 us; speedup 1.0000x reference)
//
#include <hip/hip_runtime.h>
#include <hip/hip_bf16.h>

#define F_IN 128
#define F_OUT 64
#define NPB 128            // nodes per bucket
#define LG_NPB 7
#define MAXB 1024          // static LDS sizing >= n_buckets (782)
#define BIN_BLOCKS 400
#define BIN_THREADS 512

__device__ __forceinline__ float f4c(const float4& v, int j) {
    switch (j) { case 0: return v.x; case 1: return v.y; case 2: return v.z; default: return v.w; }
}

// ---------------------------------------------------------------------------
// support(bf16) = X (N,128) @ W (128,64). 8 rows per wave.
// ---------------------------------------------------------------------------
__global__ void __launch_bounds__(256) gnn_gemm_kernel(
    const float* __restrict__ X, const float* __restrict__ W,
    __hip_bfloat16* __restrict__ support, int n_rows) {
    __shared__ float Wlds[F_IN * F_OUT];  // 32 KB
    for (int i = threadIdx.x; i < F_IN * F_OUT; i += 256) Wlds[i] = W[i];
    __syncthreads();

    const int lane = threadIdx.x & 63;
    const int wid  = threadIdx.x >> 6;
    const int row0 = (blockIdx.x * 4 + wid) * 8;
    if (row0 + 8 > n_rows) return;

    const float4* x0 = reinterpret_cast<const float4*>(X + (size_t)row0 * F_IN);
    float acc[8] = {0.f, 0.f, 0.f, 0.f, 0.f, 0.f, 0.f, 0.f};

    for (int k4 = 0; k4 < F_IN / 4; ++k4) {
        float4 xr[8];
#pragma unroll
        for (int r = 0; r < 8; ++r) xr[r] = x0[r * (F_IN / 4) + k4];
#pragma unroll
        for (int j = 0; j < 4; ++j) {
            const float w = Wlds[(k4 * 4 + j) * F_OUT + lane];
#pragma unroll
            for (int r = 0; r < 8; ++r) acc[r] = fmaf(f4c(xr[r], j), w, acc[r]);
        }
    }
#pragma unroll
    for (int r = 0; r < 8; ++r)
        support[(size_t)(row0 + r) * F_OUT + lane] = __float2bfloat16(acc[r]);
}

// ---------------------------------------------------------------------------
// Bucket histogram: block-local LDS hist -> one global atomic per bucket/block.
// ---------------------------------------------------------------------------
__global__ void __launch_bounds__(BIN_THREADS) gnn_bhist_kernel(
    const int* __restrict__ dst, int* __restrict__ gcounts, int n_edges, int n_buckets) {
    __shared__ int lcnt[MAXB];
    const int t = threadIdx.x;
    for (int i = t; i < MAXB; i += BIN_THREADS) lcnt[i] = 0;
    __syncthreads();
    const int chunk = (n_edges + gridDim.x - 1) / gridDim.x;
    const int c0 = blockIdx.x * chunk;
    const int c1 = min(c0 + chunk, n_edges);
    for (int i = c0 + t; i < c1; i += BIN_THREADS)
        atomicAdd(&lcnt[dst[i] >> LG_NPB], 1);
    __syncthreads();
    for (int b = t; b < n_buckets; b += BIN_THREADS)
        if (lcnt[b]) atomicAdd(&gcounts[b], lcnt[b]);
}

// ---------------------------------------------------------------------------
// Exclusive scan over 782 bucket counts (single block).
// ---------------------------------------------------------------------------
__global__ void __launch_bounds__(1024) gnn_bscan_kernel(
    const int* __restrict__ gcounts, int* __restrict__ starts,
    int* __restrict__ cursor, int n_buckets) {
    __shared__ int s[1024];
    const int t = threadIdx.x;
    const int v = (t < n_buckets) ? gcounts[t] : 0;
    s[t] = v;
    __syncthreads();
    for (int off = 1; off < 1024; off <<= 1) {
        int x = (t >= off) ? s[t - off] : 0;
        __syncthreads();
        s[t] += x;
        __syncthreads();
    }
    if (t < n_buckets) {
        const int st = s[t] - v;
        starts[t] = st;
        cursor[t] = st;
    }
}

// ---------------------------------------------------------------------------
// Placement: local hist -> chunk reservation per bucket -> chunked writes.
// Writes to each bucket region are ~contiguous runs (low line amplification).
// meta packs (src << 7) | (dst & 127): 24 bits. Weight kept fp32.
// ---------------------------------------------------------------------------
__global__ void __launch_bounds__(BIN_THREADS) gnn_place_kernel(
    const int* __restrict__ ei, const float* __restrict__ ew,
    int* __restrict__ cursor, int2* __restrict__ elist, int n_edges, int n_buckets) {
    __shared__ int lcnt[MAXB];
    const int t = threadIdx.x;
    for (int i = t; i < MAXB; i += BIN_THREADS) lcnt[i] = 0;
    __syncthreads();
    const int chunk = (n_edges + gridDim.x - 1) / gridDim.x;
    const int c0 = blockIdx.x * chunk;
    const int c1 = min(c0 + chunk, n_edges);
    for (int i = c0 + t; i < c1; i += BIN_THREADS)
        atomicAdd(&lcnt[ei[i] >> LG_NPB], 1);
    __syncthreads();
    for (int b = t; b < n_buckets; b += BIN_THREADS) {
        const int c = lcnt[b];
        if (c) lcnt[b] = atomicAdd(&cursor[b], c);   // lcnt[b] := global base
    }
    __syncthreads();
    for (int i = c0 + t; i < c1; i += BIN_THREADS) {
        const int d = ei[i];
        const int s = ei[n_edges + i];
        const float w = ew[i];
        const int b = d >> LG_NPB;
        const int pos = atomicAdd(&lcnt[b], 1);      // LDS atomic, returns slot
        elist[pos] = make_int2((s << LG_NPB) | (d & (NPB - 1)), __float_as_int(w));
    }
}

// ---------------------------------------------------------------------------
// Aggregate: one block per bucket; 128x64 fp32 accumulator in 32 KB LDS.
// Wave streams contiguous edge slice: broadcast meta load + 128B bf16 gather
// + conflict-free ds_add_f32. Fused ReLU epilogue, coalesced float4 writes.
// ---------------------------------------------------------------------------
__global__ void __launch_bounds__(512) gnn_agg_kernel(
    const __hip_bfloat16* __restrict__ support, const int2* __restrict__ elist,
    const int* __restrict__ starts, const int* __restrict__ gcounts,
    float* __restrict__ out, int n_nodes) {
    __shared__ float acc[NPB * F_OUT];  // 32 KB
    const int t = threadIdx.x;
    const int b = blockIdx.x;
    float4* a4 = reinterpret_cast<float4*>(acc);
    for (int i = t; i < NPB * F_OUT / 4; i += 512) a4[i] = make_float4(0.f, 0.f, 0.f, 0.f);
    __syncthreads();

    const int start = starts[b];
    const int cnt   = gcounts[b];
    const int lane  = t & 63;
    const int wave  = t >> 6;  // 0..7

    const int per = (cnt + 7) >> 3;                  // edges per wave (contiguous slice)
    const int e0  = start + wave * per;
    const int e1  = min(e0 + per, start + cnt);
#pragma unroll 4
    for (int e = e0; e < e1; ++e) {
        const int2 mm = elist[e];                    // all lanes same addr -> broadcast
        const int  src = mm.x >> LG_NPB;
        const int  dlo = mm.x & (NPB - 1);
        const float g = __bfloat162float(support[(size_t)src * F_OUT + lane]);
        atomicAdd(&acc[dlo * F_OUT + lane], g * __int_as_float(mm.y));
    }
    __syncthreads();

    const int node0  = b * NPB;
    const int nwrite = min(NPB, n_nodes - node0);
    float4* o4 = reinterpret_cast<float4*>(out + (size_t)node0 * F_OUT);
    for (int i = t; i < nwrite * F_OUT / 4; i += 512) {
        float4 v = a4[i];
        v.x = fmaxf(v.x, 0.f);
        v.y = fmaxf(v.y, 0.f);
        v.z = fmaxf(v.z, 0.f);
        v.w = fmaxf(v.w, 0.f);
        o4[i] = v;
    }
}

extern "C" void kernel_launch(void* const* d_in, const int* in_sizes, int n_in,
                              void* d_out, int out_size, void* d_ws, size_t ws_size,
                              hipStream_t stream) {
    const float* X  = (const float*)d_in[0];   // [N,128] fp32
    const float* W  = (const float*)d_in[1];   // [128,64] fp32
    const int*   EI = (const int*)d_in[2];     // [2,E] int32
    const float* EW = (const float*)d_in[3];   // [E] fp32
    float*       out = (float*)d_out;          // [N,64] fp32

    const int n_edges   = in_sizes[2] / 2;     // 1,600,000
    const int n_rows    = in_sizes[0] / F_IN;  // 100,000
    const int n_nodes   = out_size / F_OUT;    // 100,000
    const int n_buckets = (n_nodes + NPB - 1) >> LG_NPB;  // 782

    // Workspace layout (~25.6 MB)
    char* ws = (char*)d_ws;
    __hip_bfloat16* support = (__hip_bfloat16*)ws;                          // 12.8 MB
    size_t off = (size_t)n_rows * F_OUT * sizeof(__hip_bfloat16);
    int2* elist = (int2*)(ws + off);  off += (size_t)n_edges * sizeof(int2); // 12.8 MB
    int* gcounts = (int*)(ws + off);  off += MAXB * sizeof(int);
    int* starts  = (int*)(ws + off);  off += MAXB * sizeof(int);
    int* cursor  = (int*)(ws + off);

    hipMemsetAsync(gcounts, 0, (size_t)n_buckets * sizeof(int), stream);

    gnn_gemm_kernel<<<n_rows / 32, 256, 0, stream>>>(X, W, support, n_rows);
    gnn_bhist_kernel<<<BIN_BLOCKS, BIN_THREADS, 0, stream>>>(EI, gcounts, n_edges, n_buckets);
    gnn_bscan_kernel<<<1, 1024, 0, stream>>>(gcounts, starts, cursor, n_buckets);
    gnn_place_kernel<<<BIN_BLOCKS, BIN_THREADS, 0, stream>>>(EI, EW, cursor, elist, n_edges, n_buckets);
    gnn_agg_kernel<<<n_buckets, 512, 0, stream>>>(support, elist, starts, gcounts, out, n_nodes);
}

// Round 4
// 316.400 us; speedup vs baseline: 2.9148x; 2.9148x over previous
//
#include <hip/hip_runtime.h>
#include <hip/hip_bf16.h>

#define F_IN 128
#define F_OUT 64
#define NPB 128            // nodes per bucket
#define LG_NPB 7
#define MAXB 1024          // static sizing >= n_buckets (782)
#define BIN_BLOCKS 400
#define BIN_THREADS 512

__device__ __forceinline__ float f4c(const float4& v, int j) {
    switch (j) { case 0: return v.x; case 1: return v.y; case 2: return v.z; default: return v.w; }
}

// ---------------------------------------------------------------------------
// support(bf16) = X (N,128) @ W (128,64). 8 rows per wave.
// ---------------------------------------------------------------------------
__global__ void __launch_bounds__(256) gnn_gemm_kernel(
    const float* __restrict__ X, const float* __restrict__ W,
    __hip_bfloat16* __restrict__ support, int n_rows) {
    __shared__ float Wlds[F_IN * F_OUT];  // 32 KB
    for (int i = threadIdx.x; i < F_IN * F_OUT; i += 256) Wlds[i] = W[i];
    __syncthreads();

    const int lane = threadIdx.x & 63;
    const int wid  = threadIdx.x >> 6;
    const int row0 = (blockIdx.x * 4 + wid) * 8;
    if (row0 + 8 > n_rows) return;

    const float4* x0 = reinterpret_cast<const float4*>(X + (size_t)row0 * F_IN);
    float acc[8] = {0.f, 0.f, 0.f, 0.f, 0.f, 0.f, 0.f, 0.f};

    for (int k4 = 0; k4 < F_IN / 4; ++k4) {
        float4 xr[8];
#pragma unroll
        for (int r = 0; r < 8; ++r) xr[r] = x0[r * (F_IN / 4) + k4];
#pragma unroll
        for (int j = 0; j < 4; ++j) {
            const float w = Wlds[(k4 * 4 + j) * F_OUT + lane];
#pragma unroll
            for (int r = 0; r < 8; ++r) acc[r] = fmaf(f4c(xr[r], j), w, acc[r]);
        }
    }
#pragma unroll
    for (int r = 0; r < 8; ++r)
        support[(size_t)(row0 + r) * F_OUT + lane] = __float2bfloat16(acc[r]);
}

// ---------------------------------------------------------------------------
// Bucket histogram: block-local LDS hist -> one global atomic per bucket/block.
// ---------------------------------------------------------------------------
__global__ void __launch_bounds__(BIN_THREADS) gnn_bhist_kernel(
    const int* __restrict__ dst, int* __restrict__ gcounts, int n_edges, int n_buckets) {
    __shared__ int lcnt[MAXB];
    const int t = threadIdx.x;
    for (int i = t; i < MAXB; i += BIN_THREADS) lcnt[i] = 0;
    __syncthreads();
    const int chunk = (n_edges + gridDim.x - 1) / gridDim.x;
    const int c0 = blockIdx.x * chunk;
    const int c1 = min(c0 + chunk, n_edges);
    for (int i = c0 + t; i < c1; i += BIN_THREADS)
        atomicAdd(&lcnt[dst[i] >> LG_NPB], 1);
    __syncthreads();
    for (int b = t; b < n_buckets; b += BIN_THREADS)
        if (lcnt[b]) atomicAdd(&gcounts[b], lcnt[b]);
}

// ---------------------------------------------------------------------------
// Exclusive scan over bucket counts (single block).
// ---------------------------------------------------------------------------
__global__ void __launch_bounds__(1024) gnn_bscan_kernel(
    const int* __restrict__ gcounts, int* __restrict__ starts,
    int* __restrict__ cursor, int n_buckets) {
    __shared__ int s[1024];
    const int t = threadIdx.x;
    const int v = (t < n_buckets) ? gcounts[t] : 0;
    s[t] = v;
    __syncthreads();
    for (int off = 1; off < 1024; off <<= 1) {
        int x = (t >= off) ? s[t - off] : 0;
        __syncthreads();
        s[t] += x;
        __syncthreads();
    }
    if (t < n_buckets) {
        const int st = s[t] - v;
        starts[t] = st;
        cursor[t] = st;
    }
}

// ---------------------------------------------------------------------------
// Placement into bucket regions (chunk reservation -> near-contiguous runs).
// meta packs (src << 7) | (dst & 127): src < 2^17 so fits 24 bits.
// ---------------------------------------------------------------------------
__global__ void __launch_bounds__(BIN_THREADS) gnn_place_kernel(
    const int* __restrict__ ei, const float* __restrict__ ew,
    int* __restrict__ cursor, int2* __restrict__ elistA, int n_edges, int n_buckets) {
    __shared__ int lcnt[MAXB];
    const int t = threadIdx.x;
    for (int i = t; i < MAXB; i += BIN_THREADS) lcnt[i] = 0;
    __syncthreads();
    const int chunk = (n_edges + gridDim.x - 1) / gridDim.x;
    const int c0 = blockIdx.x * chunk;
    const int c1 = min(c0 + chunk, n_edges);
    for (int i = c0 + t; i < c1; i += BIN_THREADS)
        atomicAdd(&lcnt[ei[i] >> LG_NPB], 1);
    __syncthreads();
    for (int b = t; b < n_buckets; b += BIN_THREADS) {
        const int c = lcnt[b];
        if (c) lcnt[b] = atomicAdd(&cursor[b], c);   // lcnt[b] := global base
    }
    __syncthreads();
    for (int i = c0 + t; i < c1; i += BIN_THREADS) {
        const int d = ei[i];
        const int s = ei[n_edges + i];
        const float w = ew[i];
        const int b = d >> LG_NPB;
        const int pos = atomicAdd(&lcnt[b], 1);      // LDS atomic returns slot
        elistA[pos] = make_int2((s << LG_NPB) | (d & (NPB - 1)), __float_as_int(w));
    }
}

// ---------------------------------------------------------------------------
// Per-bucket counting sort by local dst: A (bucket-ordered) -> B (node-sorted).
// One block per bucket; segments are ~16 KB contiguous reads/writes.
// Also emits per-node start offsets (nstart, with sentinel at n_nodes).
// ---------------------------------------------------------------------------
__global__ void __launch_bounds__(256) gnn_sort_kernel(
    const int2* __restrict__ elistA, int2* __restrict__ elistB,
    const int* __restrict__ starts, const int* __restrict__ gcounts,
    int* __restrict__ nstart, int n_nodes, int n_buckets) {
    __shared__ int hist[NPB], pfx[NPB], cur[NPB];
    const int t = threadIdx.x;
    const int b = blockIdx.x;
    const int bstart = starts[b];
    const int cnt    = gcounts[b];

    if (t < NPB) hist[t] = 0;
    __syncthreads();
    for (int i = bstart + t; i < bstart + cnt; i += 256)
        atomicAdd(&hist[elistA[i].x & (NPB - 1)], 1);
    __syncthreads();

    // inclusive Hillis-Steele scan over 128 counters
    if (t < NPB) pfx[t] = hist[t];
    __syncthreads();
    for (int off = 1; off < NPB; off <<= 1) {
        int x = 0;
        if (t < NPB && t >= off) x = pfx[t - off];
        __syncthreads();
        if (t < NPB) pfx[t] += x;
        __syncthreads();
    }
    if (t < NPB) {
        const int excl = pfx[t] - hist[t];
        cur[t] = excl;
        const int node = b * NPB + t;
        if (node < n_nodes) nstart[node] = bstart + excl;
    }
    if (t == 0 && b == n_buckets - 1) nstart[n_nodes] = bstart + cnt;
    __syncthreads();

    for (int i = bstart + t; i < bstart + cnt; i += 256) {
        const int2 m = elistA[i];
        const int dlo = m.x & (NPB - 1);
        const int pos = bstart + atomicAdd(&cur[dlo], 1);
        elistB[pos] = make_int2(m.x >> LG_NPB, m.y);   // full src + weight
    }
}

// ---------------------------------------------------------------------------
// Pull: one wave per node, lane = feature. Register accumulation, 4-deep
// manual load pipeline, fused ReLU, plain coalesced writes. No atomics.
// ---------------------------------------------------------------------------
__global__ void __launch_bounds__(256) gnn_pull_kernel(
    const __hip_bfloat16* __restrict__ support, const int2* __restrict__ elist,
    const int* __restrict__ nstart, float* __restrict__ out, int n_nodes) {
    const int lane = threadIdx.x & 63;
    const int node = (blockIdx.x * 256 + threadIdx.x) >> 6;
    if (node >= n_nodes) return;

    const int s0 = nstart[node];
    const int s1 = nstart[node + 1];

    float acc = 0.f;
    int e = s0;
    for (; e + 4 <= s1; e += 4) {
        const int2 m0 = elist[e];
        const int2 m1 = elist[e + 1];
        const int2 m2 = elist[e + 2];
        const int2 m3 = elist[e + 3];
        const float g0 = __bfloat162float(support[(size_t)m0.x * F_OUT + lane]);
        const float g1 = __bfloat162float(support[(size_t)m1.x * F_OUT + lane]);
        const float g2 = __bfloat162float(support[(size_t)m2.x * F_OUT + lane]);
        const float g3 = __bfloat162float(support[(size_t)m3.x * F_OUT + lane]);
        acc = fmaf(__int_as_float(m0.y), g0, acc);
        acc = fmaf(__int_as_float(m1.y), g1, acc);
        acc = fmaf(__int_as_float(m2.y), g2, acc);
        acc = fmaf(__int_as_float(m3.y), g3, acc);
    }
    for (; e < s1; ++e) {
        const int2 m = elist[e];
        acc = fmaf(__int_as_float(m.y),
                   __bfloat162float(support[(size_t)m.x * F_OUT + lane]), acc);
    }
    out[(size_t)node * F_OUT + lane] = fmaxf(acc, 0.f);
}

extern "C" void kernel_launch(void* const* d_in, const int* in_sizes, int n_in,
                              void* d_out, int out_size, void* d_ws, size_t ws_size,
                              hipStream_t stream) {
    const float* X  = (const float*)d_in[0];   // [N,128] fp32
    const float* W  = (const float*)d_in[1];   // [128,64] fp32
    const int*   EI = (const int*)d_in[2];     // [2,E] int32
    const float* EW = (const float*)d_in[3];   // [E] fp32
    float*       out = (float*)d_out;          // [N,64] fp32

    const int n_edges   = in_sizes[2] / 2;     // 1,600,000
    const int n_rows    = in_sizes[0] / F_IN;  // 100,000
    const int n_nodes   = out_size / F_OUT;    // 100,000
    const int n_buckets = (n_nodes + NPB - 1) >> LG_NPB;  // 782

    // Workspace layout (~26.4 MB). Region A is reused: first as the
    // bucket-ordered edge list, then (after sort A->B) as bf16 support.
    char* ws = (char*)d_ws;
    int2* elistA = (int2*)ws;                                  // 12.8 MB (A)
    __hip_bfloat16* support = (__hip_bfloat16*)ws;             // A reused
    size_t off = (size_t)n_edges * sizeof(int2);
    int2* elistB = (int2*)(ws + off); off += (size_t)n_edges * sizeof(int2);  // 12.8 MB (B)
    int* gcounts = (int*)(ws + off);  off += MAXB * sizeof(int);
    int* starts  = (int*)(ws + off);  off += MAXB * sizeof(int);
    int* cursor  = (int*)(ws + off);  off += MAXB * sizeof(int);
    int* nstart  = (int*)(ws + off);  // n_nodes + 1 ints (~400 KB)

    hipMemsetAsync(gcounts, 0, (size_t)n_buckets * sizeof(int), stream);

    gnn_bhist_kernel<<<BIN_BLOCKS, BIN_THREADS, 0, stream>>>(EI, gcounts, n_edges, n_buckets);
    gnn_bscan_kernel<<<1, 1024, 0, stream>>>(gcounts, starts, cursor, n_buckets);
    gnn_place_kernel<<<BIN_BLOCKS, BIN_THREADS, 0, stream>>>(EI, EW, cursor, elistA, n_edges, n_buckets);
    gnn_sort_kernel<<<n_buckets, 256, 0, stream>>>(elistA, elistB, starts, gcounts,
                                                   nstart, n_nodes, n_buckets);
    gnn_gemm_kernel<<<n_rows / 32, 256, 0, stream>>>(X, W, support, n_rows);  // overwrites A
    gnn_pull_kernel<<<(n_nodes * F_OUT) / 256, 256, 0, stream>>>(support, elistB, nstart, out, n_nodes);
}

// Round 5
// 248.918 us; speedup vs baseline: 3.7050x; 1.2711x over previous
//
#include <hip/hip_runtime.h>
#include <hip/hip_bf16.h>

#define F_IN 128
#define F_OUT 64
#define NPB 128            // nodes per bucket
#define LG_NPB 7
#define MAXB 1024          // static sizing >= n_buckets (782)
#define BIN_BLOCKS 400
#define BIN_THREADS 512

#define GEMM_RT 256        // rows per block tile
#define GEMM_KC 16         // k-chunk staged in LDS
#define XT_STRIDE (GEMM_RT + 4)   // 260 words; 16B-aligned rows, low conflicts

// ---------------------------------------------------------------------------
// support(bf16) = X (N,128) @ W (128,64), fp32 register-blocked tile GEMM.
// X staged transposed in LDS via coalesced lane-distinct float4 loads
// (fixes the wave-uniform-load bandwidth wall: 16B/instr -> 1KB/instr).
// Per-thread 8x8 output tile: 4 ds_read_b128 per k feed 64 FMAs.
// ---------------------------------------------------------------------------
__global__ void __launch_bounds__(256) gnn_gemm_kernel(
    const float* __restrict__ X, const float* __restrict__ W,
    __hip_bfloat16* __restrict__ support, int n_rows) {
    __shared__ float Wlds[F_IN * F_OUT];            // 32 KB, [k][c]
    __shared__ float Xt[GEMM_KC * XT_STRIDE];       // 16.6 KB, [k][r] transposed chunk
    const int t = threadIdx.x;
    for (int i = t; i < F_IN * F_OUT; i += 256) Wlds[i] = W[i];

    const int row0 = blockIdx.x * GEMM_RT;
    const int ti = t >> 3;           // 0..31 row-group (8 rows each)
    const int tj = t & 7;            // 0..7  col-group (8 cols each)
    const int r0 = ti * 8;
    const int c0 = tj * 8;

    float acc[8][8];
#pragma unroll
    for (int r = 0; r < 8; ++r)
#pragma unroll
        for (int c = 0; c < 8; ++c) acc[r][c] = 0.f;

    for (int kc = 0; kc < F_IN; kc += GEMM_KC) {
        __syncthreads();             // protect Xt from previous chunk's readers
        // Stage X[row0..row0+255][kc..kc+15] transposed: Xt[k][r].
        // 256 rows x 16 k = 1024 float4 loads; 4 per thread, fully coalesced.
#pragma unroll
        for (int v = 0; v < 4; ++v) {
            const int idx = t + v * 256;            // 0..1023
            const int r   = idx >> 2;               // 0..255
            const int k4  = (idx & 3) * 4;          // 0,4,8,12
            float4 xv = make_float4(0.f, 0.f, 0.f, 0.f);
            if (row0 + r < n_rows)
                xv = *reinterpret_cast<const float4*>(
                    X + (size_t)(row0 + r) * F_IN + kc + k4);
            Xt[(k4 + 0) * XT_STRIDE + r] = xv.x;
            Xt[(k4 + 1) * XT_STRIDE + r] = xv.y;
            Xt[(k4 + 2) * XT_STRIDE + r] = xv.z;
            Xt[(k4 + 3) * XT_STRIDE + r] = xv.w;
        }
        __syncthreads();
#pragma unroll 4
        for (int kk = 0; kk < GEMM_KC; ++kk) {
            const float4 xa = *reinterpret_cast<const float4*>(&Xt[kk * XT_STRIDE + r0]);
            const float4 xb = *reinterpret_cast<const float4*>(&Xt[kk * XT_STRIDE + r0 + 4]);
            const float4 wa = *reinterpret_cast<const float4*>(&Wlds[(kc + kk) * F_OUT + c0]);
            const float4 wb = *reinterpret_cast<const float4*>(&Wlds[(kc + kk) * F_OUT + c0 + 4]);
            const float xr[8] = {xa.x, xa.y, xa.z, xa.w, xb.x, xb.y, xb.z, xb.w};
            const float wc[8] = {wa.x, wa.y, wa.z, wa.w, wb.x, wb.y, wb.z, wb.w};
#pragma unroll
            for (int r = 0; r < 8; ++r)
#pragma unroll
                for (int c = 0; c < 8; ++c)
                    acc[r][c] = fmaf(xr[r], wc[c], acc[r][c]);
        }
    }

    // Epilogue: bf16 pack, 16B stores (8 cols per row per thread).
#pragma unroll
    for (int r = 0; r < 8; ++r) {
        const int row = row0 + r0 + r;
        if (row < n_rows) {
            union { __hip_bfloat16 h[8]; uint4 u; } pk;
#pragma unroll
            for (int c = 0; c < 8; ++c) pk.h[c] = __float2bfloat16(acc[r][c]);
            *reinterpret_cast<uint4*>(support + (size_t)row * F_OUT + c0) = pk.u;
        }
    }
}

// ---------------------------------------------------------------------------
// Bucket histogram: block-local LDS hist -> one global atomic per bucket/block.
// ---------------------------------------------------------------------------
__global__ void __launch_bounds__(BIN_THREADS) gnn_bhist_kernel(
    const int* __restrict__ dst, int* __restrict__ gcounts, int n_edges, int n_buckets) {
    __shared__ int lcnt[MAXB];
    const int t = threadIdx.x;
    for (int i = t; i < MAXB; i += BIN_THREADS) lcnt[i] = 0;
    __syncthreads();
    const int chunk = (n_edges + gridDim.x - 1) / gridDim.x;
    const int c0 = blockIdx.x * chunk;
    const int c1 = min(c0 + chunk, n_edges);
    for (int i = c0 + t; i < c1; i += BIN_THREADS)
        atomicAdd(&lcnt[dst[i] >> LG_NPB], 1);
    __syncthreads();
    for (int b = t; b < n_buckets; b += BIN_THREADS)
        if (lcnt[b]) atomicAdd(&gcounts[b], lcnt[b]);
}

// ---------------------------------------------------------------------------
// Exclusive scan over bucket counts (single block).
// ---------------------------------------------------------------------------
__global__ void __launch_bounds__(1024) gnn_bscan_kernel(
    const int* __restrict__ gcounts, int* __restrict__ starts,
    int* __restrict__ cursor, int n_buckets) {
    __shared__ int s[1024];
    const int t = threadIdx.x;
    const int v = (t < n_buckets) ? gcounts[t] : 0;
    s[t] = v;
    __syncthreads();
    for (int off = 1; off < 1024; off <<= 1) {
        int x = (t >= off) ? s[t - off] : 0;
        __syncthreads();
        s[t] += x;
        __syncthreads();
    }
    if (t < n_buckets) {
        const int st = s[t] - v;
        starts[t] = st;
        cursor[t] = st;
    }
}

// ---------------------------------------------------------------------------
// Placement into bucket regions (chunk reservation -> near-contiguous runs).
// meta packs (src << 7) | (dst & 127): src < 2^17 so fits 24 bits.
// ---------------------------------------------------------------------------
__global__ void __launch_bounds__(BIN_THREADS) gnn_place_kernel(
    const int* __restrict__ ei, const float* __restrict__ ew,
    int* __restrict__ cursor, int2* __restrict__ elistA, int n_edges, int n_buckets) {
    __shared__ int lcnt[MAXB];
    const int t = threadIdx.x;
    for (int i = t; i < MAXB; i += BIN_THREADS) lcnt[i] = 0;
    __syncthreads();
    const int chunk = (n_edges + gridDim.x - 1) / gridDim.x;
    const int c0 = blockIdx.x * chunk;
    const int c1 = min(c0 + chunk, n_edges);
    for (int i = c0 + t; i < c1; i += BIN_THREADS)
        atomicAdd(&lcnt[ei[i] >> LG_NPB], 1);
    __syncthreads();
    for (int b = t; b < n_buckets; b += BIN_THREADS) {
        const int c = lcnt[b];
        if (c) lcnt[b] = atomicAdd(&cursor[b], c);   // lcnt[b] := global base
    }
    __syncthreads();
    for (int i = c0 + t; i < c1; i += BIN_THREADS) {
        const int d = ei[i];
        const int s = ei[n_edges + i];
        const float w = ew[i];
        const int b = d >> LG_NPB;
        const int pos = atomicAdd(&lcnt[b], 1);      // LDS atomic returns slot
        elistA[pos] = make_int2((s << LG_NPB) | (d & (NPB - 1)), __float_as_int(w));
    }
}

// ---------------------------------------------------------------------------
// Per-bucket counting sort by local dst: A (bucket-ordered) -> B (node-sorted).
// Also emits per-node start offsets (nstart, sentinel at n_nodes).
// ---------------------------------------------------------------------------
__global__ void __launch_bounds__(256) gnn_sort_kernel(
    const int2* __restrict__ elistA, int2* __restrict__ elistB,
    const int* __restrict__ starts, const int* __restrict__ gcounts,
    int* __restrict__ nstart, int n_nodes, int n_buckets) {
    __shared__ int hist[NPB], pfx[NPB], cur[NPB];
    const int t = threadIdx.x;
    const int b = blockIdx.x;
    const int bstart = starts[b];
    const int cnt    = gcounts[b];

    if (t < NPB) hist[t] = 0;
    __syncthreads();
    for (int i = bstart + t; i < bstart + cnt; i += 256)
        atomicAdd(&hist[elistA[i].x & (NPB - 1)], 1);
    __syncthreads();

    if (t < NPB) pfx[t] = hist[t];
    __syncthreads();
    for (int off = 1; off < NPB; off <<= 1) {
        int x = 0;
        if (t < NPB && t >= off) x = pfx[t - off];
        __syncthreads();
        if (t < NPB) pfx[t] += x;
        __syncthreads();
    }
    if (t < NPB) {
        const int excl = pfx[t] - hist[t];
        cur[t] = excl;
        const int node = b * NPB + t;
        if (node < n_nodes) nstart[node] = bstart + excl;
    }
    if (t == 0 && b == n_buckets - 1) nstart[n_nodes] = bstart + cnt;
    __syncthreads();

    for (int i = bstart + t; i < bstart + cnt; i += 256) {
        const int2 m = elistA[i];
        const int dlo = m.x & (NPB - 1);
        const int pos = bstart + atomicAdd(&cur[dlo], 1);
        elistB[pos] = make_int2(m.x >> LG_NPB, m.y);   // full src + weight
    }
}

// ---------------------------------------------------------------------------
// Pull: one wave per node, lane = feature. Register accumulation, 4-deep
// manual load pipeline, fused ReLU, plain coalesced writes. No atomics.
// ---------------------------------------------------------------------------
__global__ void __launch_bounds__(256) gnn_pull_kernel(
    const __hip_bfloat16* __restrict__ support, const int2* __restrict__ elist,
    const int* __restrict__ nstart, float* __restrict__ out, int n_nodes) {
    const int lane = threadIdx.x & 63;
    const int node = (blockIdx.x * 256 + threadIdx.x) >> 6;
    if (node >= n_nodes) return;

    const int s0 = nstart[node];
    const int s1 = nstart[node + 1];

    float acc = 0.f;
    int e = s0;
    for (; e + 4 <= s1; e += 4) {
        const int2 m0 = elist[e];
        const int2 m1 = elist[e + 1];
        const int2 m2 = elist[e + 2];
        const int2 m3 = elist[e + 3];
        const float g0 = __bfloat162float(support[(size_t)m0.x * F_OUT + lane]);
        const float g1 = __bfloat162float(support[(size_t)m1.x * F_OUT + lane]);
        const float g2 = __bfloat162float(support[(size_t)m2.x * F_OUT + lane]);
        const float g3 = __bfloat162float(support[(size_t)m3.x * F_OUT + lane]);
        acc = fmaf(__int_as_float(m0.y), g0, acc);
        acc = fmaf(__int_as_float(m1.y), g1, acc);
        acc = fmaf(__int_as_float(m2.y), g2, acc);
        acc = fmaf(__int_as_float(m3.y), g3, acc);
    }
    for (; e < s1; ++e) {
        const int2 m = elist[e];
        acc = fmaf(__int_as_float(m.y),
                   __bfloat162float(support[(size_t)m.x * F_OUT + lane]), acc);
    }
    out[(size_t)node * F_OUT + lane] = fmaxf(acc, 0.f);
}

extern "C" void kernel_launch(void* const* d_in, const int* in_sizes, int n_in,
                              void* d_out, int out_size, void* d_ws, size_t ws_size,
                              hipStream_t stream) {
    const float* X  = (const float*)d_in[0];   // [N,128] fp32
    const float* W  = (const float*)d_in[1];   // [128,64] fp32
    const int*   EI = (const int*)d_in[2];     // [2,E] int32
    const float* EW = (const float*)d_in[3];   // [E] fp32
    float*       out = (float*)d_out;          // [N,64] fp32

    const int n_edges   = in_sizes[2] / 2;     // 1,600,000
    const int n_rows    = in_sizes[0] / F_IN;  // 100,000
    const int n_nodes   = out_size / F_OUT;    // 100,000
    const int n_buckets = (n_nodes + NPB - 1) >> LG_NPB;  // 782

    // Workspace layout (~26.4 MB). Region A is reused: first as the
    // bucket-ordered edge list, then (after sort A->B) as bf16 support.
    char* ws = (char*)d_ws;
    int2* elistA = (int2*)ws;                                  // 12.8 MB (A)
    __hip_bfloat16* support = (__hip_bfloat16*)ws;             // A reused
    size_t off = (size_t)n_edges * sizeof(int2);
    int2* elistB = (int2*)(ws + off); off += (size_t)n_edges * sizeof(int2);  // 12.8 MB (B)
    int* gcounts = (int*)(ws + off);  off += MAXB * sizeof(int);
    int* starts  = (int*)(ws + off);  off += MAXB * sizeof(int);
    int* cursor  = (int*)(ws + off);  off += MAXB * sizeof(int);
    int* nstart  = (int*)(ws + off);  // n_nodes + 1 ints (~400 KB)

    hipMemsetAsync(gcounts, 0, (size_t)n_buckets * sizeof(int), stream);

    gnn_bhist_kernel<<<BIN_BLOCKS, BIN_THREADS, 0, stream>>>(EI, gcounts, n_edges, n_buckets);
    gnn_bscan_kernel<<<1, 1024, 0, stream>>>(gcounts, starts, cursor, n_buckets);
    gnn_place_kernel<<<BIN_BLOCKS, BIN_THREADS, 0, stream>>>(EI, EW, cursor, elistA, n_edges, n_buckets);
    gnn_sort_kernel<<<n_buckets, 256, 0, stream>>>(elistA, elistB, starts, gcounts,
                                                   nstart, n_nodes, n_buckets);
    gnn_gemm_kernel<<<(n_rows + GEMM_RT - 1) / GEMM_RT, 256, 0, stream>>>(X, W, support, n_rows);
    gnn_pull_kernel<<<(n_nodes * F_OUT) / 256, 256, 0, stream>>>(support, elistB, nstart, out, n_nodes);
}

// Round 6
// 215.358 us; speedup vs baseline: 4.2823x; 1.1558x over previous
//
#include <hip/hip_runtime.h>
#include <hip/hip_bf16.h>

#define F_IN 128
#define F_OUT 64
#define NPB 128            // nodes per bucket
#define LG_NPB 7
#define MAXB 1024          // static sizing >= n_buckets (782)
#define BIN_BLOCKS 400
#define BIN_THREADS 512
#define SORT_CAP 4096      // LDS edge capacity per bucket (mean 2046, sd ~45)

#define GEMM_RT 256        // rows per block tile
#define GEMM_KC 16         // k-chunk staged in LDS
#define XT_STRIDE (GEMM_RT + 4)

// ---------------------------------------------------------------------------
// support(bf16) = X (N,128) @ W (128,64), fp32 register-blocked tile GEMM.
// ---------------------------------------------------------------------------
__global__ void __launch_bounds__(256) gnn_gemm_kernel(
    const float* __restrict__ X, const float* __restrict__ W,
    __hip_bfloat16* __restrict__ support, int n_rows) {
    __shared__ float Wlds[F_IN * F_OUT];            // 32 KB, [k][c]
    __shared__ float Xt[GEMM_KC * XT_STRIDE];       // 16.6 KB, [k][r]
    const int t = threadIdx.x;
    for (int i = t; i < F_IN * F_OUT; i += 256) Wlds[i] = W[i];

    const int row0 = blockIdx.x * GEMM_RT;
    const int ti = t >> 3;
    const int tj = t & 7;
    const int r0 = ti * 8;
    const int c0 = tj * 8;

    float acc[8][8];
#pragma unroll
    for (int r = 0; r < 8; ++r)
#pragma unroll
        for (int c = 0; c < 8; ++c) acc[r][c] = 0.f;

    for (int kc = 0; kc < F_IN; kc += GEMM_KC) {
        __syncthreads();
#pragma unroll
        for (int v = 0; v < 4; ++v) {
            const int idx = t + v * 256;
            const int r   = idx >> 2;
            const int k4  = (idx & 3) * 4;
            float4 xv = make_float4(0.f, 0.f, 0.f, 0.f);
            if (row0 + r < n_rows)
                xv = *reinterpret_cast<const float4*>(
                    X + (size_t)(row0 + r) * F_IN + kc + k4);
            Xt[(k4 + 0) * XT_STRIDE + r] = xv.x;
            Xt[(k4 + 1) * XT_STRIDE + r] = xv.y;
            Xt[(k4 + 2) * XT_STRIDE + r] = xv.z;
            Xt[(k4 + 3) * XT_STRIDE + r] = xv.w;
        }
        __syncthreads();
#pragma unroll 4
        for (int kk = 0; kk < GEMM_KC; ++kk) {
            const float4 xa = *reinterpret_cast<const float4*>(&Xt[kk * XT_STRIDE + r0]);
            const float4 xb = *reinterpret_cast<const float4*>(&Xt[kk * XT_STRIDE + r0 + 4]);
            const float4 wa = *reinterpret_cast<const float4*>(&Wlds[(kc + kk) * F_OUT + c0]);
            const float4 wb = *reinterpret_cast<const float4*>(&Wlds[(kc + kk) * F_OUT + c0 + 4]);
            const float xr[8] = {xa.x, xa.y, xa.z, xa.w, xb.x, xb.y, xb.z, xb.w};
            const float wc[8] = {wa.x, wa.y, wa.z, wa.w, wb.x, wb.y, wb.z, wb.w};
#pragma unroll
            for (int r = 0; r < 8; ++r)
#pragma unroll
                for (int c = 0; c < 8; ++c)
                    acc[r][c] = fmaf(xr[r], wc[c], acc[r][c]);
        }
    }

#pragma unroll
    for (int r = 0; r < 8; ++r) {
        const int row = row0 + r0 + r;
        if (row < n_rows) {
            union { __hip_bfloat16 h[8]; uint4 u; } pk;
#pragma unroll
            for (int c = 0; c < 8; ++c) pk.h[c] = __float2bfloat16(acc[r][c]);
            *reinterpret_cast<uint4*>(support + (size_t)row * F_OUT + c0) = pk.u;
        }
    }
}

// ---------------------------------------------------------------------------
// Bucket histogram: block-local LDS hist -> one global atomic per bucket/block.
// ---------------------------------------------------------------------------
__global__ void __launch_bounds__(BIN_THREADS) gnn_bhist_kernel(
    const int* __restrict__ dst, int* __restrict__ gcounts, int n_edges, int n_buckets) {
    __shared__ int lcnt[MAXB];
    const int t = threadIdx.x;
    for (int i = t; i < MAXB; i += BIN_THREADS) lcnt[i] = 0;
    __syncthreads();
    const int chunk = (n_edges + gridDim.x - 1) / gridDim.x;
    const int c0 = blockIdx.x * chunk;
    const int c1 = min(c0 + chunk, n_edges);
    for (int i = c0 + t; i < c1; i += BIN_THREADS)
        atomicAdd(&lcnt[dst[i] >> LG_NPB], 1);
    __syncthreads();
    for (int b = t; b < n_buckets; b += BIN_THREADS)
        if (lcnt[b]) atomicAdd(&gcounts[b], lcnt[b]);
}

// ---------------------------------------------------------------------------
// Exclusive scan over bucket counts (single block).
// ---------------------------------------------------------------------------
__global__ void __launch_bounds__(1024) gnn_bscan_kernel(
    const int* __restrict__ gcounts, int* __restrict__ starts,
    int* __restrict__ cursor, int n_buckets) {
    __shared__ int s[1024];
    const int t = threadIdx.x;
    const int v = (t < n_buckets) ? gcounts[t] : 0;
    s[t] = v;
    __syncthreads();
    for (int off = 1; off < 1024; off <<= 1) {
        int x = (t >= off) ? s[t - off] : 0;
        __syncthreads();
        s[t] += x;
        __syncthreads();
    }
    if (t < n_buckets) {
        const int st = s[t] - v;
        starts[t] = st;
        cursor[t] = st;
    }
}

// ---------------------------------------------------------------------------
// Placement into bucket regions (chunk reservation -> near-contiguous runs).
// meta packs (src << 7) | (dst & 127).
// ---------------------------------------------------------------------------
__global__ void __launch_bounds__(BIN_THREADS) gnn_place_kernel(
    const int* __restrict__ ei, const float* __restrict__ ew,
    int* __restrict__ cursor, int2* __restrict__ elistA, int n_edges, int n_buckets) {
    __shared__ int lcnt[MAXB];
    const int t = threadIdx.x;
    for (int i = t; i < MAXB; i += BIN_THREADS) lcnt[i] = 0;
    __syncthreads();
    const int chunk = (n_edges + gridDim.x - 1) / gridDim.x;
    const int c0 = blockIdx.x * chunk;
    const int c1 = min(c0 + chunk, n_edges);
    for (int i = c0 + t; i < c1; i += BIN_THREADS)
        atomicAdd(&lcnt[ei[i] >> LG_NPB], 1);
    __syncthreads();
    for (int b = t; b < n_buckets; b += BIN_THREADS) {
        const int c = lcnt[b];
        if (c) lcnt[b] = atomicAdd(&cursor[b], c);   // lcnt[b] := global base
    }
    __syncthreads();
    for (int i = c0 + t; i < c1; i += BIN_THREADS) {
        const int d = ei[i];
        const int s = ei[n_edges + i];
        const float w = ew[i];
        const int b = d >> LG_NPB;
        const int pos = atomicAdd(&lcnt[b], 1);      // LDS atomic returns slot
        elistA[pos] = make_int2((s << LG_NPB) | (d & (NPB - 1)), __float_as_int(w));
    }
}

// ---------------------------------------------------------------------------
// Merged sort+pull: one block per bucket.
// Phase 1: counting-sort bucket's edges into LDS (by dst&127).
// Phase 2: 8 waves x 16 nodes; meta from LDS (broadcast reads), 8-deep
//          gather pipeline, register accumulation, fused ReLU, 128B writes.
// Eliminates elistB round-trip (25.6 MB) + nstart + one dispatch, and
// replaces 1.6M wave-uniform global meta loads with LDS broadcasts.
// ---------------------------------------------------------------------------
__global__ void __launch_bounds__(512) gnn_sortpull_kernel(
    const __hip_bfloat16* __restrict__ support, const int2* __restrict__ elistA,
    const int* __restrict__ starts, const int* __restrict__ gcounts,
    float* __restrict__ out, int n_nodes) {
    __shared__ int2 smeta[SORT_CAP];      // 32 KB sorted (src, w) list
    __shared__ int hist[NPB];
    __shared__ int pfx[NPB];
    __shared__ int segs[NPB + 1];         // per-node segment starts (+sentinel)
    __shared__ int cur[NPB];
    const int t = threadIdx.x;
    const int b = blockIdx.x;
    const int bstart = starts[b];
    const int cnt    = min(gcounts[b], SORT_CAP);   // cap is 45 sigma; never clamps

    if (t < NPB) hist[t] = 0;
    __syncthreads();
    for (int i = t; i < cnt; i += 512)
        atomicAdd(&hist[elistA[bstart + i].x & (NPB - 1)], 1);
    __syncthreads();

    if (t < NPB) pfx[t] = hist[t];
    __syncthreads();
    for (int off = 1; off < NPB; off <<= 1) {
        int x = 0;
        if (t < NPB && t >= off) x = pfx[t - off];
        __syncthreads();
        if (t < NPB) pfx[t] += x;
        __syncthreads();
    }
    if (t < NPB) {
        const int st = pfx[t] - hist[t];   // exclusive
        segs[t] = st;
        cur[t]  = st;
    }
    if (t == 0) segs[NPB] = cnt;
    __syncthreads();

    for (int i = t; i < cnt; i += 512) {
        const int2 m = elistA[bstart + i];
        const int dlo = m.x & (NPB - 1);
        const int pos = atomicAdd(&cur[dlo], 1);
        smeta[pos] = make_int2(m.x >> LG_NPB, m.y);
    }
    __syncthreads();

    const int lane = t & 63;
    const int wave = t >> 6;              // 0..7
    for (int n = wave; n < NPB; n += 8) {
        const int node = b * NPB + n;
        if (node >= n_nodes) break;
        int e  = segs[n];
        const int e1 = segs[n + 1];
        float acc = 0.f;
        for (; e + 8 <= e1; e += 8) {
            int2 m[8];
#pragma unroll
            for (int u = 0; u < 8; ++u) m[u] = smeta[e + u];
            float g[8];
#pragma unroll
            for (int u = 0; u < 8; ++u)
                g[u] = __bfloat162float(support[(size_t)m[u].x * F_OUT + lane]);
#pragma unroll
            for (int u = 0; u < 8; ++u)
                acc = fmaf(__int_as_float(m[u].y), g[u], acc);
        }
        for (; e + 2 <= e1; e += 2) {
            const int2 m0 = smeta[e];
            const int2 m1 = smeta[e + 1];
            const float g0 = __bfloat162float(support[(size_t)m0.x * F_OUT + lane]);
            const float g1 = __bfloat162float(support[(size_t)m1.x * F_OUT + lane]);
            acc = fmaf(__int_as_float(m0.y), g0, acc);
            acc = fmaf(__int_as_float(m1.y), g1, acc);
        }
        if (e < e1) {
            const int2 m0 = smeta[e];
            acc = fmaf(__int_as_float(m0.y),
                       __bfloat162float(support[(size_t)m0.x * F_OUT + lane]), acc);
        }
        out[(size_t)node * F_OUT + lane] = fmaxf(acc, 0.f);
    }
}

extern "C" void kernel_launch(void* const* d_in, const int* in_sizes, int n_in,
                              void* d_out, int out_size, void* d_ws, size_t ws_size,
                              hipStream_t stream) {
    const float* X  = (const float*)d_in[0];   // [N,128] fp32
    const float* W  = (const float*)d_in[1];   // [128,64] fp32
    const int*   EI = (const int*)d_in[2];     // [2,E] int32
    const float* EW = (const float*)d_in[3];   // [E] fp32
    float*       out = (float*)d_out;          // [N,64] fp32

    const int n_edges   = in_sizes[2] / 2;     // 1,600,000
    const int n_rows    = in_sizes[0] / F_IN;  // 100,000
    const int n_nodes   = out_size / F_OUT;    // 100,000
    const int n_buckets = (n_nodes + NPB - 1) >> LG_NPB;  // 782

    // Workspace (~25.7 MB): support and elistA now coexist (no reuse trick).
    char* ws = (char*)d_ws;
    __hip_bfloat16* support = (__hip_bfloat16*)ws;             // 12.8 MB
    size_t off = (size_t)n_rows * F_OUT * sizeof(__hip_bfloat16);
    int2* elistA = (int2*)(ws + off); off += (size_t)n_edges * sizeof(int2);  // 12.8 MB
    int* gcounts = (int*)(ws + off);  off += MAXB * sizeof(int);
    int* starts  = (int*)(ws + off);  off += MAXB * sizeof(int);
    int* cursor  = (int*)(ws + off);

    hipMemsetAsync(gcounts, 0, (size_t)n_buckets * sizeof(int), stream);

    gnn_bhist_kernel<<<BIN_BLOCKS, BIN_THREADS, 0, stream>>>(EI, gcounts, n_edges, n_buckets);
    gnn_bscan_kernel<<<1, 1024, 0, stream>>>(gcounts, starts, cursor, n_buckets);
    gnn_place_kernel<<<BIN_BLOCKS, BIN_THREADS, 0, stream>>>(EI, EW, cursor, elistA, n_edges, n_buckets);
    gnn_gemm_kernel<<<(n_rows + GEMM_RT - 1) / GEMM_RT, 256, 0, stream>>>(X, W, support, n_rows);
    gnn_sortpull_kernel<<<n_buckets, 512, 0, stream>>>(support, elistA, starts, gcounts, out, n_nodes);
}

// Round 7
// 202.795 us; speedup vs baseline: 4.5476x; 1.0619x over previous
//
#include <hip/hip_runtime.h>
#include <hip/hip_bf16.h>

#define F_IN 128
#define F_OUT 64
#define NPB 128            // nodes per bucket
#define LG_NPB 7
#define MAXB 1024          // static sizing >= n_buckets (782)
#define BIN_BLOCKS 400
#define BIN_THREADS 512
#define SORT_CAP 4096      // LDS edge capacity per bucket (mean 2046, sd ~45)

#define GEMM_RT 128        // rows per block tile (782 blocks -> 3 blocks/CU)
#define GEMM_KC 16         // k-chunk staged in LDS
#define XT_STRIDE (GEMM_RT + 4)   // 132 floats; 528B rows (16B-multiple)

// ---------------------------------------------------------------------------
// support(bf16) = X (N,128) @ W (128,64), fp32 register-blocked tile GEMM.
// RT=128: grid 782 blocks (3/CU), LDS 40.4 KB, acc[4][8] -> ~12 waves/CU.
// ---------------------------------------------------------------------------
__global__ void __launch_bounds__(256) gnn_gemm_kernel(
    const float* __restrict__ X, const float* __restrict__ W,
    __hip_bfloat16* __restrict__ support, int n_rows) {
    __shared__ float Wlds[F_IN * F_OUT];            // 32 KB, [k][c]
    __shared__ float Xt[GEMM_KC * XT_STRIDE];       // 8.4 KB, [k][r]
    const int t = threadIdx.x;
    for (int i = t; i < F_IN * F_OUT; i += 256) Wlds[i] = W[i];

    const int row0 = blockIdx.x * GEMM_RT;
    const int ti = t >> 3;           // 0..31 -> 4-row group
    const int tj = t & 7;            // 0..7  -> 8-col group
    const int r0 = ti * 4;
    const int c0 = tj * 8;

    float acc[4][8];
#pragma unroll
    for (int r = 0; r < 4; ++r)
#pragma unroll
        for (int c = 0; c < 8; ++c) acc[r][c] = 0.f;

    for (int kc = 0; kc < F_IN; kc += GEMM_KC) {
        __syncthreads();             // protect Xt (also covers initial Wlds fill)
        // Stage X[row0..row0+127][kc..kc+15] transposed: 512 float4 loads.
#pragma unroll
        for (int v = 0; v < 2; ++v) {
            const int idx = t + v * 256;            // 0..511
            const int r   = idx >> 2;               // 0..127
            const int k4  = (idx & 3) * 4;          // 0,4,8,12
            float4 xv = make_float4(0.f, 0.f, 0.f, 0.f);
            if (row0 + r < n_rows)
                xv = *reinterpret_cast<const float4*>(
                    X + (size_t)(row0 + r) * F_IN + kc + k4);
            Xt[(k4 + 0) * XT_STRIDE + r] = xv.x;
            Xt[(k4 + 1) * XT_STRIDE + r] = xv.y;
            Xt[(k4 + 2) * XT_STRIDE + r] = xv.z;
            Xt[(k4 + 3) * XT_STRIDE + r] = xv.w;
        }
        __syncthreads();
#pragma unroll 4
        for (int kk = 0; kk < GEMM_KC; ++kk) {
            const float4 xa = *reinterpret_cast<const float4*>(&Xt[kk * XT_STRIDE + r0]);
            const float4 wa = *reinterpret_cast<const float4*>(&Wlds[(kc + kk) * F_OUT + c0]);
            const float4 wb = *reinterpret_cast<const float4*>(&Wlds[(kc + kk) * F_OUT + c0 + 4]);
            const float xr[4] = {xa.x, xa.y, xa.z, xa.w};
            const float wc[8] = {wa.x, wa.y, wa.z, wa.w, wb.x, wb.y, wb.z, wb.w};
#pragma unroll
            for (int r = 0; r < 4; ++r)
#pragma unroll
                for (int c = 0; c < 8; ++c)
                    acc[r][c] = fmaf(xr[r], wc[c], acc[r][c]);
        }
    }

#pragma unroll
    for (int r = 0; r < 4; ++r) {
        const int row = row0 + r0 + r;
        if (row < n_rows) {
            union { __hip_bfloat16 h[8]; uint4 u; } pk;
#pragma unroll
            for (int c = 0; c < 8; ++c) pk.h[c] = __float2bfloat16(acc[r][c]);
            *reinterpret_cast<uint4*>(support + (size_t)row * F_OUT + c0) = pk.u;
        }
    }
}

// ---------------------------------------------------------------------------
// Bucket histogram: int4-vectorized dst reads, block-local LDS hist,
// one global atomic per bucket per block.
// ---------------------------------------------------------------------------
__global__ void __launch_bounds__(BIN_THREADS) gnn_bhist_kernel(
    const int* __restrict__ dst, int* __restrict__ gcounts, int n_edges, int n_buckets) {
    __shared__ int lcnt[MAXB];
    const int t = threadIdx.x;
    for (int i = t; i < MAXB; i += BIN_THREADS) lcnt[i] = 0;
    __syncthreads();
    int chunk = (n_edges + gridDim.x - 1) / gridDim.x;
    chunk = (chunk + 3) & ~3;                       // keep c0 int4-aligned
    const int c0 = min((int)(blockIdx.x * chunk), n_edges);
    const int c1 = min(c0 + chunk, n_edges);
    const int nv = (c1 - c0) >> 2;                  // int4 count
    const int4* d4 = reinterpret_cast<const int4*>(dst + c0);
    for (int i = t; i < nv; i += BIN_THREADS) {
        const int4 d = d4[i];
        atomicAdd(&lcnt[d.x >> LG_NPB], 1);
        atomicAdd(&lcnt[d.y >> LG_NPB], 1);
        atomicAdd(&lcnt[d.z >> LG_NPB], 1);
        atomicAdd(&lcnt[d.w >> LG_NPB], 1);
    }
    for (int i = c0 + (nv << 2) + t; i < c1; i += BIN_THREADS)
        atomicAdd(&lcnt[dst[i] >> LG_NPB], 1);
    __syncthreads();
    for (int b = t; b < n_buckets; b += BIN_THREADS)
        if (lcnt[b]) atomicAdd(&gcounts[b], lcnt[b]);
}

// ---------------------------------------------------------------------------
// Exclusive scan over bucket counts (single block).
// ---------------------------------------------------------------------------
__global__ void __launch_bounds__(1024) gnn_bscan_kernel(
    const int* __restrict__ gcounts, int* __restrict__ starts,
    int* __restrict__ cursor, int n_buckets) {
    __shared__ int s[1024];
    const int t = threadIdx.x;
    const int v = (t < n_buckets) ? gcounts[t] : 0;
    s[t] = v;
    __syncthreads();
    for (int off = 1; off < 1024; off <<= 1) {
        int x = (t >= off) ? s[t - off] : 0;
        __syncthreads();
        s[t] += x;
        __syncthreads();
    }
    if (t < n_buckets) {
        const int st = s[t] - v;
        starts[t] = st;
        cursor[t] = st;
    }
}

// ---------------------------------------------------------------------------
// Placement into bucket regions, int4/float4-vectorized edge reads.
// meta packs (src << 7) | (dst & 127).
// ---------------------------------------------------------------------------
__global__ void __launch_bounds__(BIN_THREADS) gnn_place_kernel(
    const int* __restrict__ ei, const float* __restrict__ ew,
    int* __restrict__ cursor, int2* __restrict__ elistA, int n_edges, int n_buckets) {
    __shared__ int lcnt[MAXB];
    const int t = threadIdx.x;
    for (int i = t; i < MAXB; i += BIN_THREADS) lcnt[i] = 0;
    __syncthreads();
    int chunk = (n_edges + gridDim.x - 1) / gridDim.x;
    chunk = (chunk + 3) & ~3;
    const int c0 = min((int)(blockIdx.x * chunk), n_edges);
    const int c1 = min(c0 + chunk, n_edges);
    const int nv = (c1 - c0) >> 2;
    const int4* d4 = reinterpret_cast<const int4*>(ei + c0);

    for (int i = t; i < nv; i += BIN_THREADS) {
        const int4 d = d4[i];
        atomicAdd(&lcnt[d.x >> LG_NPB], 1);
        atomicAdd(&lcnt[d.y >> LG_NPB], 1);
        atomicAdd(&lcnt[d.z >> LG_NPB], 1);
        atomicAdd(&lcnt[d.w >> LG_NPB], 1);
    }
    for (int i = c0 + (nv << 2) + t; i < c1; i += BIN_THREADS)
        atomicAdd(&lcnt[ei[i] >> LG_NPB], 1);
    __syncthreads();
    for (int b = t; b < n_buckets; b += BIN_THREADS) {
        const int c = lcnt[b];
        if (c) lcnt[b] = atomicAdd(&cursor[b], c);   // lcnt[b] := global base
    }
    __syncthreads();

    const int4*   s4 = reinterpret_cast<const int4*>(ei + n_edges + c0);
    const float4* w4 = reinterpret_cast<const float4*>(ew + c0);
    for (int i = t; i < nv; i += BIN_THREADS) {
        const int4 d = d4[i];
        const int4 s = s4[i];
        const float4 w = w4[i];
        const int dd[4] = {d.x, d.y, d.z, d.w};
        const int ss[4] = {s.x, s.y, s.z, s.w};
        const float ww[4] = {w.x, w.y, w.z, w.w};
#pragma unroll
        for (int u = 0; u < 4; ++u) {
            const int b = dd[u] >> LG_NPB;
            const int pos = atomicAdd(&lcnt[b], 1);
            elistA[pos] = make_int2((ss[u] << LG_NPB) | (dd[u] & (NPB - 1)),
                                    __float_as_int(ww[u]));
        }
    }
    for (int i = c0 + (nv << 2) + t; i < c1; i += BIN_THREADS) {
        const int d = ei[i];
        const int s = ei[n_edges + i];
        const int b = d >> LG_NPB;
        const int pos = atomicAdd(&lcnt[b], 1);
        elistA[pos] = make_int2((s << LG_NPB) | (d & (NPB - 1)),
                                __float_as_int(ew[i]));
    }
}

// ---------------------------------------------------------------------------
// Merged sort+pull: one block per bucket. Counting-sort edges into LDS
// (smeta.x holds src byte-offset = src*128), then 8 waves x 16 nodes pull
// with 8-deep gather pipeline, register accumulation, fused ReLU.
// ---------------------------------------------------------------------------
__global__ void __launch_bounds__(512) gnn_sortpull_kernel(
    const __hip_bfloat16* __restrict__ support, const int2* __restrict__ elistA,
    const int* __restrict__ starts, const int* __restrict__ gcounts,
    float* __restrict__ out, int n_nodes) {
    __shared__ int2 smeta[SORT_CAP];      // 32 KB sorted (src_byteoff, w) list
    __shared__ int hist[NPB];
    __shared__ int pfx[NPB];
    __shared__ int segs[NPB + 1];
    __shared__ int cur[NPB];
    const int t = threadIdx.x;
    const int b = blockIdx.x;
    const int bstart = starts[b];
    const int cnt    = min(gcounts[b], SORT_CAP);   // cap is 45 sigma; never clamps

    if (t < NPB) hist[t] = 0;
    __syncthreads();
    for (int i = t; i < cnt; i += 512)
        atomicAdd(&hist[elistA[bstart + i].x & (NPB - 1)], 1);
    __syncthreads();

    if (t < NPB) pfx[t] = hist[t];
    __syncthreads();
    for (int off = 1; off < NPB; off <<= 1) {
        int x = 0;
        if (t < NPB && t >= off) x = pfx[t - off];
        __syncthreads();
        if (t < NPB) pfx[t] += x;
        __syncthreads();
    }
    if (t < NPB) {
        const int st = pfx[t] - hist[t];   // exclusive
        segs[t] = st;
        cur[t]  = st;
    }
    if (t == 0) segs[NPB] = cnt;
    __syncthreads();

    for (int i = t; i < cnt; i += 512) {
        const int2 m = elistA[bstart + i];
        const int dlo = m.x & (NPB - 1);
        const int pos = atomicAdd(&cur[dlo], 1);
        // src byte offset: (m.x>>7)<<7 == m.x with low 7 bits cleared
        // (F_OUT * sizeof(bf16) = 128 bytes per support row)
        smeta[pos] = make_int2(m.x & ~(NPB - 1), m.y);
    }
    __syncthreads();

    const char* sp = reinterpret_cast<const char*>(support);
    const int lane = t & 63;
    const int wave = t >> 6;              // 0..7
    for (int n = wave; n < NPB; n += 8) {
        const int node = b * NPB + n;
        if (node >= n_nodes) break;
        int e  = segs[n];
        const int e1 = segs[n + 1];
        float acc = 0.f;
        for (; e + 8 <= e1; e += 8) {
            int2 m[8];
#pragma unroll
            for (int u = 0; u < 8; ++u) m[u] = smeta[e + u];
            float g[8];
#pragma unroll
            for (int u = 0; u < 8; ++u)
                g[u] = __bfloat162float(
                    *reinterpret_cast<const __hip_bfloat16*>(sp + m[u].x + lane * 2));
#pragma unroll
            for (int u = 0; u < 8; ++u)
                acc = fmaf(__int_as_float(m[u].y), g[u], acc);
        }
        for (; e + 2 <= e1; e += 2) {
            const int2 m0 = smeta[e];
            const int2 m1 = smeta[e + 1];
            const float g0 = __bfloat162float(
                *reinterpret_cast<const __hip_bfloat16*>(sp + m0.x + lane * 2));
            const float g1 = __bfloat162float(
                *reinterpret_cast<const __hip_bfloat16*>(sp + m1.x + lane * 2));
            acc = fmaf(__int_as_float(m0.y), g0, acc);
            acc = fmaf(__int_as_float(m1.y), g1, acc);
        }
        if (e < e1) {
            const int2 m0 = smeta[e];
            acc = fmaf(__int_as_float(m0.y),
                       __bfloat162float(
                           *reinterpret_cast<const __hip_bfloat16*>(sp + m0.x + lane * 2)),
                       acc);
        }
        out[(size_t)node * F_OUT + lane] = fmaxf(acc, 0.f);
    }
}

extern "C" void kernel_launch(void* const* d_in, const int* in_sizes, int n_in,
                              void* d_out, int out_size, void* d_ws, size_t ws_size,
                              hipStream_t stream) {
    const float* X  = (const float*)d_in[0];   // [N,128] fp32
    const float* W  = (const float*)d_in[1];   // [128,64] fp32
    const int*   EI = (const int*)d_in[2];     // [2,E] int32
    const float* EW = (const float*)d_in[3];   // [E] fp32
    float*       out = (float*)d_out;          // [N,64] fp32

    const int n_edges   = in_sizes[2] / 2;     // 1,600,000
    const int n_rows    = in_sizes[0] / F_IN;  // 100,000
    const int n_nodes   = out_size / F_OUT;    // 100,000
    const int n_buckets = (n_nodes + NPB - 1) >> LG_NPB;  // 782

    // Workspace (~25.7 MB)
    char* ws = (char*)d_ws;
    __hip_bfloat16* support = (__hip_bfloat16*)ws;             // 12.8 MB
    size_t off = (size_t)n_rows * F_OUT * sizeof(__hip_bfloat16);
    int2* elistA = (int2*)(ws + off); off += (size_t)n_edges * sizeof(int2);  // 12.8 MB
    int* gcounts = (int*)(ws + off);  off += MAXB * sizeof(int);
    int* starts  = (int*)(ws + off);  off += MAXB * sizeof(int);
    int* cursor  = (int*)(ws + off);

    hipMemsetAsync(gcounts, 0, (size_t)n_buckets * sizeof(int), stream);

    gnn_bhist_kernel<<<BIN_BLOCKS, BIN_THREADS, 0, stream>>>(EI, gcounts, n_edges, n_buckets);
    gnn_bscan_kernel<<<1, 1024, 0, stream>>>(gcounts, starts, cursor, n_buckets);
    gnn_place_kernel<<<BIN_BLOCKS, BIN_THREADS, 0, stream>>>(EI, EW, cursor, elistA, n_edges, n_buckets);
    gnn_gemm_kernel<<<(n_rows + GEMM_RT - 1) / GEMM_RT, 256, 0, stream>>>(X, W, support, n_rows);
    gnn_sortpull_kernel<<<n_buckets, 512, 0, stream>>>(support, elistA, starts, gcounts, out, n_nodes);
}

// Round 9
// 201.972 us; speedup vs baseline: 4.5662x; 1.0041x over previous
//
#include <hip/hip_runtime.h>
#include <hip/hip_bf16.h>

#define F_IN 128
#define F_OUT 64
#define NPB 128            // nodes per bucket
#define LG_NPB 7
#define MAXB 1024          // static sizing >= n_buckets (782)
#define BIN_BLOCKS 784
#define BIN_THREADS 512
#define SORT_CAP 4096      // LDS edge capacity per bucket (mean 2046, sd ~45)

typedef float  f32x4  __attribute__((ext_vector_type(4)));
typedef short  bf16x8 __attribute__((ext_vector_type(8)));

__device__ __forceinline__ short f2bf(float f) {
    union { __hip_bfloat16 h; short s; } u;
    u.h = __float2bfloat16(f);
    return u.s;
}

// ---------------------------------------------------------------------------
// support(bf16) = X (N,128) @ W (128,64) via mfma_f32_16x16x32_bf16.
// No LDS, no barriers. Per wave: W held as 16 B-fragments in VGPRs (loaded
// once, L2-resident); per 16-row M-block: A-fragments load straight from X
// rows (lane l holds X[m0+(l&15)][ks*32+(l>>4)*8 ..+7] = two float4 loads),
// 16 MFMA (4 k-steps x 4 col-tiles), C stored per m89 layout
// (col=lane&15, row=(lane>>4)*4+reg). n_rows % 16 == 0 (100000).
// ---------------------------------------------------------------------------
__global__ void __launch_bounds__(256) gnn_gemm_kernel(
    const float* __restrict__ X, const float* __restrict__ W,
    __hip_bfloat16* __restrict__ support, int n_rows) {
    const int lane   = threadIdx.x & 63;
    const int gwave  = (blockIdx.x * 256 + threadIdx.x) >> 6;
    const int nwaves = (gridDim.x * 256) >> 6;

    // B-fragments: lane holds B[k=(l>>4)*8+j][col=l&15] for each
    // (ks: k-step of 32) x (ct: 16-col tile).
    const int bcol = lane & 15;
    const int bk0  = (lane >> 4) * 8;
    bf16x8 bfrag[4][4];
#pragma unroll
    for (int ks = 0; ks < 4; ++ks)
#pragma unroll
        for (int ct = 0; ct < 4; ++ct) {
            bf16x8 f;
#pragma unroll
            for (int j = 0; j < 8; ++j)
                f[j] = f2bf(W[(ks * 32 + bk0 + j) * F_OUT + ct * 16 + bcol]);
            bfrag[ks][ct] = f;
        }

    const int arow = lane & 15;
    const int ak0  = (lane >> 4) * 8;
    const int crow = (lane >> 4) * 4;
    const int nmb  = n_rows >> 4;          // 6250 M-blocks

    for (int mb = gwave; mb < nmb; mb += nwaves) {
        const int m0 = mb << 4;
        const float* xrow = X + (size_t)(m0 + arow) * F_IN + ak0;

        // Issue all 8 X loads up front (MLP), then convert + MFMA.
        float4 xv[4][2];
#pragma unroll
        for (int ks = 0; ks < 4; ++ks) {
            xv[ks][0] = *reinterpret_cast<const float4*>(xrow + ks * 32);
            xv[ks][1] = *reinterpret_cast<const float4*>(xrow + ks * 32 + 4);
        }

        f32x4 acc[4];
#pragma unroll
        for (int ct = 0; ct < 4; ++ct) acc[ct] = (f32x4){0.f, 0.f, 0.f, 0.f};

#pragma unroll
        for (int ks = 0; ks < 4; ++ks) {
            bf16x8 af;
            af[0] = f2bf(xv[ks][0].x); af[1] = f2bf(xv[ks][0].y);
            af[2] = f2bf(xv[ks][0].z); af[3] = f2bf(xv[ks][0].w);
            af[4] = f2bf(xv[ks][1].x); af[5] = f2bf(xv[ks][1].y);
            af[6] = f2bf(xv[ks][1].z); af[7] = f2bf(xv[ks][1].w);
#pragma unroll
            for (int ct = 0; ct < 4; ++ct)
                acc[ct] = __builtin_amdgcn_mfma_f32_16x16x32_bf16(
                    af, bfrag[ks][ct], acc[ct], 0, 0, 0);
        }

#pragma unroll
        for (int ct = 0; ct < 4; ++ct)
#pragma unroll
            for (int r = 0; r < 4; ++r)
                support[(size_t)(m0 + crow + r) * F_OUT + ct * 16 + bcol] =
                    __float2bfloat16(acc[ct][r]);
    }
}

// ---------------------------------------------------------------------------
// Bucket histogram: int4-vectorized dst reads, block-local LDS hist,
// one global atomic per bucket per block.
// ---------------------------------------------------------------------------
__global__ void __launch_bounds__(BIN_THREADS) gnn_bhist_kernel(
    const int* __restrict__ dst, int* __restrict__ gcounts, int n_edges, int n_buckets) {
    __shared__ int lcnt[MAXB];
    const int t = threadIdx.x;
    for (int i = t; i < MAXB; i += BIN_THREADS) lcnt[i] = 0;
    __syncthreads();
    int chunk = (n_edges + gridDim.x - 1) / gridDim.x;
    chunk = (chunk + 3) & ~3;
    const int c0 = min((int)(blockIdx.x * chunk), n_edges);
    const int c1 = min(c0 + chunk, n_edges);
    const int nv = (c1 - c0) >> 2;
    const int4* d4 = reinterpret_cast<const int4*>(dst + c0);
    for (int i = t; i < nv; i += BIN_THREADS) {
        const int4 d = d4[i];
        atomicAdd(&lcnt[d.x >> LG_NPB], 1);
        atomicAdd(&lcnt[d.y >> LG_NPB], 1);
        atomicAdd(&lcnt[d.z >> LG_NPB], 1);
        atomicAdd(&lcnt[d.w >> LG_NPB], 1);
    }
    for (int i = c0 + (nv << 2) + t; i < c1; i += BIN_THREADS)
        atomicAdd(&lcnt[dst[i] >> LG_NPB], 1);
    __syncthreads();
    for (int b = t; b < n_buckets; b += BIN_THREADS)
        if (lcnt[b]) atomicAdd(&gcounts[b], lcnt[b]);
}

// ---------------------------------------------------------------------------
// Exclusive scan over bucket counts (single block).
// ---------------------------------------------------------------------------
__global__ void __launch_bounds__(1024) gnn_bscan_kernel(
    const int* __restrict__ gcounts, int* __restrict__ starts,
    int* __restrict__ cursor, int n_buckets) {
    __shared__ int s[1024];
    const int t = threadIdx.x;
    const int v = (t < n_buckets) ? gcounts[t] : 0;
    s[t] = v;
    __syncthreads();
    for (int off = 1; off < 1024; off <<= 1) {
        int x = (t >= off) ? s[t - off] : 0;
        __syncthreads();
        s[t] += x;
        __syncthreads();
    }
    if (t < n_buckets) {
        const int st = s[t] - v;
        starts[t] = st;
        cursor[t] = st;
    }
}

// ---------------------------------------------------------------------------
// Placement into bucket regions, int4/float4-vectorized edge reads.
// meta packs (src << 7) | (dst & 127).
// ---------------------------------------------------------------------------
__global__ void __launch_bounds__(BIN_THREADS) gnn_place_kernel(
    const int* __restrict__ ei, const float* __restrict__ ew,
    int* __restrict__ cursor, int2* __restrict__ elistA, int n_edges, int n_buckets) {
    __shared__ int lcnt[MAXB];
    const int t = threadIdx.x;
    for (int i = t; i < MAXB; i += BIN_THREADS) lcnt[i] = 0;
    __syncthreads();
    int chunk = (n_edges + gridDim.x - 1) / gridDim.x;
    chunk = (chunk + 3) & ~3;
    const int c0 = min((int)(blockIdx.x * chunk), n_edges);
    const int c1 = min(c0 + chunk, n_edges);
    const int nv = (c1 - c0) >> 2;
    const int4* d4 = reinterpret_cast<const int4*>(ei + c0);

    for (int i = t; i < nv; i += BIN_THREADS) {
        const int4 d = d4[i];
        atomicAdd(&lcnt[d.x >> LG_NPB], 1);
        atomicAdd(&lcnt[d.y >> LG_NPB], 1);
        atomicAdd(&lcnt[d.z >> LG_NPB], 1);
        atomicAdd(&lcnt[d.w >> LG_NPB], 1);
    }
    for (int i = c0 + (nv << 2) + t; i < c1; i += BIN_THREADS)
        atomicAdd(&lcnt[ei[i] >> LG_NPB], 1);
    __syncthreads();
    for (int b = t; b < n_buckets; b += BIN_THREADS) {
        const int c = lcnt[b];
        if (c) lcnt[b] = atomicAdd(&cursor[b], c);   // lcnt[b] := global base
    }
    __syncthreads();

    const int4*   s4 = reinterpret_cast<const int4*>(ei + n_edges + c0);
    const float4* w4 = reinterpret_cast<const float4*>(ew + c0);
    for (int i = t; i < nv; i += BIN_THREADS) {
        const int4 d = d4[i];
        const int4 s = s4[i];
        const float4 w = w4[i];
        const int dd[4] = {d.x, d.y, d.z, d.w};
        const int ss[4] = {s.x, s.y, s.z, s.w};
        const float ww[4] = {w.x, w.y, w.z, w.w};
#pragma unroll
        for (int u = 0; u < 4; ++u) {
            const int b = dd[u] >> LG_NPB;
            const int pos = atomicAdd(&lcnt[b], 1);
            elistA[pos] = make_int2((ss[u] << LG_NPB) | (dd[u] & (NPB - 1)),
                                    __float_as_int(ww[u]));
        }
    }
    for (int i = c0 + (nv << 2) + t; i < c1; i += BIN_THREADS) {
        const int d = ei[i];
        const int s = ei[n_edges + i];
        const int b = d >> LG_NPB;
        const int pos = atomicAdd(&lcnt[b], 1);
        elistA[pos] = make_int2((s << LG_NPB) | (d & (NPB - 1)),
                                __float_as_int(ew[i]));
    }
}

// ---------------------------------------------------------------------------
// Merged sort+pull: one block per bucket. Counting-sort edges into LDS
// (smeta.x holds src byte-offset = src*128), then 8 waves x 16 nodes pull
// with 8-deep gather pipeline, register accumulation, fused ReLU.
// ---------------------------------------------------------------------------
__global__ void __launch_bounds__(512) gnn_sortpull_kernel(
    const __hip_bfloat16* __restrict__ support, const int2* __restrict__ elistA,
    const int* __restrict__ starts, const int* __restrict__ gcounts,
    float* __restrict__ out, int n_nodes) {
    __shared__ int2 smeta[SORT_CAP];      // 32 KB sorted (src_byteoff, w) list
    __shared__ int hist[NPB];
    __shared__ int pfx[NPB];
    __shared__ int segs[NPB + 1];
    __shared__ int cur[NPB];
    const int t = threadIdx.x;
    const int b = blockIdx.x;
    const int bstart = starts[b];
    const int cnt    = min(gcounts[b], SORT_CAP);   // cap is 45 sigma; never clamps

    if (t < NPB) hist[t] = 0;
    __syncthreads();
    for (int i = t; i < cnt; i += 512)
        atomicAdd(&hist[elistA[bstart + i].x & (NPB - 1)], 1);
    __syncthreads();

    if (t < NPB) pfx[t] = hist[t];
    __syncthreads();
    for (int off = 1; off < NPB; off <<= 1) {
        int x = 0;
        if (t < NPB && t >= off) x = pfx[t - off];
        __syncthreads();
        if (t < NPB) pfx[t] += x;
        __syncthreads();
    }
    if (t < NPB) {
        const int st = pfx[t] - hist[t];   // exclusive
        segs[t] = st;
        cur[t]  = st;
    }
    if (t == 0) segs[NPB] = cnt;
    __syncthreads();

    for (int i = t; i < cnt; i += 512) {
        const int2 m = elistA[bstart + i];
        const int dlo = m.x & (NPB - 1);
        const int pos = atomicAdd(&cur[dlo], 1);
        smeta[pos] = make_int2(m.x & ~(NPB - 1), m.y);   // src*128 byte offset
    }
    __syncthreads();

    const char* sp = reinterpret_cast<const char*>(support);
    const int lane = t & 63;
    const int wave = t >> 6;              // 0..7
    for (int n = wave; n < NPB; n += 8) {
        const int node = b * NPB + n;
        if (node >= n_nodes) break;
        int e  = segs[n];
        const int e1 = segs[n + 1];
        float acc = 0.f;
        for (; e + 8 <= e1; e += 8) {
            int2 m[8];
#pragma unroll
            for (int u = 0; u < 8; ++u) m[u] = smeta[e + u];
            float g[8];
#pragma unroll
            for (int u = 0; u < 8; ++u)
                g[u] = __bfloat162float(
                    *reinterpret_cast<const __hip_bfloat16*>(sp + m[u].x + lane * 2));
#pragma unroll
            for (int u = 0; u < 8; ++u)
                acc = fmaf(__int_as_float(m[u].y), g[u], acc);
        }
        for (; e + 2 <= e1; e += 2) {
            const int2 m0 = smeta[e];
            const int2 m1 = smeta[e + 1];
            const float g0 = __bfloat162float(
                *reinterpret_cast<const __hip_bfloat16*>(sp + m0.x + lane * 2));
            const float g1 = __bfloat162float(
                *reinterpret_cast<const __hip_bfloat16*>(sp + m1.x + lane * 2));
            acc = fmaf(__int_as_float(m0.y), g0, acc);
            acc = fmaf(__int_as_float(m1.y), g1, acc);
        }
        if (e < e1) {
            const int2 m0 = smeta[e];
            acc = fmaf(__int_as_float(m0.y),
                       __bfloat162float(
                           *reinterpret_cast<const __hip_bfloat16*>(sp + m0.x + lane * 2)),
                       acc);
        }
        out[(size_t)node * F_OUT + lane] = fmaxf(acc, 0.f);
    }
}

extern "C" void kernel_launch(void* const* d_in, const int* in_sizes, int n_in,
                              void* d_out, int out_size, void* d_ws, size_t ws_size,
                              hipStream_t stream) {
    const float* X  = (const float*)d_in[0];   // [N,128] fp32
    const float* W  = (const float*)d_in[1];   // [128,64] fp32
    const int*   EI = (const int*)d_in[2];     // [2,E] int32
    const float* EW = (const float*)d_in[3];   // [E] fp32
    float*       out = (float*)d_out;          // [N,64] fp32

    const int n_edges   = in_sizes[2] / 2;     // 1,600,000
    const int n_rows    = in_sizes[0] / F_IN;  // 100,000
    const int n_nodes   = out_size / F_OUT;    // 100,000
    const int n_buckets = (n_nodes + NPB - 1) >> LG_NPB;  // 782

    // Workspace (~25.7 MB)
    char* ws = (char*)d_ws;
    __hip_bfloat16* support = (__hip_bfloat16*)ws;             // 12.8 MB
    size_t off = (size_t)n_rows * F_OUT * sizeof(__hip_bfloat16);
    int2* elistA = (int2*)(ws + off); off += (size_t)n_edges * sizeof(int2);  // 12.8 MB
    int* gcounts = (int*)(ws + off);  off += MAXB * sizeof(int);
    int* starts  = (int*)(ws + off);  off += MAXB * sizeof(int);
    int* cursor  = (int*)(ws + off);

    hipMemsetAsync(gcounts, 0, (size_t)n_buckets * sizeof(int), stream);

    gnn_bhist_kernel<<<BIN_BLOCKS, BIN_THREADS, 0, stream>>>(EI, gcounts, n_edges, n_buckets);
    gnn_bscan_kernel<<<1, 1024, 0, stream>>>(gcounts, starts, cursor, n_buckets);
    gnn_place_kernel<<<BIN_BLOCKS, BIN_THREADS, 0, stream>>>(EI, EW, cursor, elistA, n_edges, n_buckets);
    gnn_gemm_kernel<<<512, 256, 0, stream>>>(X, W, support, n_rows);
    gnn_sortpull_kernel<<<n_buckets, 512, 0, stream>>>(support, elistA, starts, gcounts, out, n_nodes);
}

// Round 10
// 197.611 us; speedup vs baseline: 4.6669x; 1.0221x over previous
//
#include <hip/hip_runtime.h>
#include <hip/hip_bf16.h>

#define F_IN 128
#define F_OUT 64
#define NPB 128            // nodes per bucket
#define LG_NPB 7
#define MAXB 1024          // static sizing >= n_buckets (782)
#define BIN_BLOCKS 784
#define BIN_THREADS 512
#define SORT_CAP 4096      // LDS edge capacity per bucket (mean 2046, sd ~45)
#define PLACE_CHUNK 4000   // edges per place block (32 KB staging)

typedef float  f32x4  __attribute__((ext_vector_type(4)));
typedef short  bf16x8 __attribute__((ext_vector_type(8)));

__device__ __forceinline__ short f2bf(float f) {
    union { __hip_bfloat16 h; short s; } u;
    u.h = __float2bfloat16(f);
    return u.s;
}

// ---------------------------------------------------------------------------
// support(bf16) = X (N,128) @ W (128,64) via mfma_f32_16x16x32_bf16.
// No LDS, no barriers. W held as 16 B-fragments in VGPRs; A-fragments load
// straight from X rows. C layout per m89: col=lane&15, row=(lane>>4)*4+reg.
// ---------------------------------------------------------------------------
__global__ void __launch_bounds__(256) gnn_gemm_kernel(
    const float* __restrict__ X, const float* __restrict__ W,
    __hip_bfloat16* __restrict__ support, int n_rows) {
    const int lane   = threadIdx.x & 63;
    const int gwave  = (blockIdx.x * 256 + threadIdx.x) >> 6;
    const int nwaves = (gridDim.x * 256) >> 6;

    const int bcol = lane & 15;
    const int bk0  = (lane >> 4) * 8;
    bf16x8 bfrag[4][4];
#pragma unroll
    for (int ks = 0; ks < 4; ++ks)
#pragma unroll
        for (int ct = 0; ct < 4; ++ct) {
            bf16x8 f;
#pragma unroll
            for (int j = 0; j < 8; ++j)
                f[j] = f2bf(W[(ks * 32 + bk0 + j) * F_OUT + ct * 16 + bcol]);
            bfrag[ks][ct] = f;
        }

    const int arow = lane & 15;
    const int ak0  = (lane >> 4) * 8;
    const int crow = (lane >> 4) * 4;
    const int nmb  = n_rows >> 4;

    for (int mb = gwave; mb < nmb; mb += nwaves) {
        const int m0 = mb << 4;
        const float* xrow = X + (size_t)(m0 + arow) * F_IN + ak0;

        float4 xv[4][2];
#pragma unroll
        for (int ks = 0; ks < 4; ++ks) {
            xv[ks][0] = *reinterpret_cast<const float4*>(xrow + ks * 32);
            xv[ks][1] = *reinterpret_cast<const float4*>(xrow + ks * 32 + 4);
        }

        f32x4 acc[4];
#pragma unroll
        for (int ct = 0; ct < 4; ++ct) acc[ct] = (f32x4){0.f, 0.f, 0.f, 0.f};

#pragma unroll
        for (int ks = 0; ks < 4; ++ks) {
            bf16x8 af;
            af[0] = f2bf(xv[ks][0].x); af[1] = f2bf(xv[ks][0].y);
            af[2] = f2bf(xv[ks][0].z); af[3] = f2bf(xv[ks][0].w);
            af[4] = f2bf(xv[ks][1].x); af[5] = f2bf(xv[ks][1].y);
            af[6] = f2bf(xv[ks][1].z); af[7] = f2bf(xv[ks][1].w);
#pragma unroll
            for (int ct = 0; ct < 4; ++ct)
                acc[ct] = __builtin_amdgcn_mfma_f32_16x16x32_bf16(
                    af, bfrag[ks][ct], acc[ct], 0, 0, 0);
        }

#pragma unroll
        for (int ct = 0; ct < 4; ++ct)
#pragma unroll
            for (int r = 0; r < 4; ++r)
                support[(size_t)(m0 + crow + r) * F_OUT + ct * 16 + bcol] =
                    __float2bfloat16(acc[ct][r]);
    }
}

// ---------------------------------------------------------------------------
// Bucket histogram: int4-vectorized dst reads, block-local LDS hist,
// one global atomic per bucket per block.
// ---------------------------------------------------------------------------
__global__ void __launch_bounds__(BIN_THREADS) gnn_bhist_kernel(
    const int* __restrict__ dst, int* __restrict__ gcounts, int n_edges, int n_buckets) {
    __shared__ int lcnt[MAXB];
    const int t = threadIdx.x;
    for (int i = t; i < MAXB; i += BIN_THREADS) lcnt[i] = 0;
    __syncthreads();
    int chunk = (n_edges + gridDim.x - 1) / gridDim.x;
    chunk = (chunk + 3) & ~3;
    const int c0 = min((int)(blockIdx.x * chunk), n_edges);
    const int c1 = min(c0 + chunk, n_edges);
    const int nv = (c1 - c0) >> 2;
    const int4* d4 = reinterpret_cast<const int4*>(dst + c0);
    for (int i = t; i < nv; i += BIN_THREADS) {
        const int4 d = d4[i];
        atomicAdd(&lcnt[d.x >> LG_NPB], 1);
        atomicAdd(&lcnt[d.y >> LG_NPB], 1);
        atomicAdd(&lcnt[d.z >> LG_NPB], 1);
        atomicAdd(&lcnt[d.w >> LG_NPB], 1);
    }
    for (int i = c0 + (nv << 2) + t; i < c1; i += BIN_THREADS)
        atomicAdd(&lcnt[dst[i] >> LG_NPB], 1);
    __syncthreads();
    for (int b = t; b < n_buckets; b += BIN_THREADS)
        if (lcnt[b]) atomicAdd(&gcounts[b], lcnt[b]);
}

// ---------------------------------------------------------------------------
// Exclusive scan over bucket counts (single block).
// ---------------------------------------------------------------------------
__global__ void __launch_bounds__(1024) gnn_bscan_kernel(
    const int* __restrict__ gcounts, int* __restrict__ starts,
    int* __restrict__ cursor, int n_buckets) {
    __shared__ int s[1024];
    const int t = threadIdx.x;
    const int v = (t < n_buckets) ? gcounts[t] : 0;
    s[t] = v;
    __syncthreads();
    for (int off = 1; off < 1024; off <<= 1) {
        int x = (t >= off) ? s[t - off] : 0;
        __syncthreads();
        s[t] += x;
        __syncthreads();
    }
    if (t < n_buckets) {
        const int st = s[t] - v;
        starts[t] = st;
        cursor[t] = st;
    }
}

// ---------------------------------------------------------------------------
// Placement v2: block-local LDS counting sort -> bucket-contiguous writes.
// Per block (4000 edges): LDS hist -> local exclusive scan (1024 via 512x2)
// -> reserve one global chunk per bucket -> scatter into LDS staging grouped
// by bucket -> write out contiguous runs (~10 edges = 80 B each).
// Eliminates the random-8B-store line-RMW amplification of the old place.
// ---------------------------------------------------------------------------
__global__ void __launch_bounds__(512) gnn_place_kernel(
    const int* __restrict__ ei, const float* __restrict__ ew,
    int* __restrict__ cursor, int2* __restrict__ elistA, int n_edges, int n_buckets) {
    __shared__ int  lcnt[MAXB];               // 4 KB
    __shared__ int  ps[512];                  // 2 KB
    __shared__ int  lstart[MAXB];             // 4 KB
    __shared__ int  cur[MAXB];                // 4 KB
    __shared__ int  gbase[MAXB];              // 4 KB
    __shared__ int2 stg[PLACE_CHUNK];         // 32 KB
    __shared__ unsigned short sbkt[PLACE_CHUNK];  // 8 KB   (total 58 KB)
    const int t = threadIdx.x;
    for (int i = t; i < MAXB; i += 512) lcnt[i] = 0;
    __syncthreads();

    const int c0  = min((int)(blockIdx.x * PLACE_CHUNK), n_edges);
    const int c1  = min(c0 + PLACE_CHUNK, n_edges);
    const int cnt = c1 - c0;
    const int nv  = cnt >> 2;
    const int4* d4 = reinterpret_cast<const int4*>(ei + c0);

    // Phase 1: local histogram.
    for (int i = t; i < nv; i += 512) {
        const int4 d = d4[i];
        atomicAdd(&lcnt[d.x >> LG_NPB], 1);
        atomicAdd(&lcnt[d.y >> LG_NPB], 1);
        atomicAdd(&lcnt[d.z >> LG_NPB], 1);
        atomicAdd(&lcnt[d.w >> LG_NPB], 1);
    }
    for (int i = c0 + (nv << 2) + t; i < c1; i += 512)
        atomicAdd(&lcnt[ei[i] >> LG_NPB], 1);
    __syncthreads();

    // Phase 2: local exclusive scan over 1024 counters (512 threads x 2).
    const int a0 = lcnt[2 * t];
    const int a1 = lcnt[2 * t + 1];
    ps[t] = a0 + a1;
    __syncthreads();
    for (int off = 1; off < 512; off <<= 1) {
        int x = (t >= off) ? ps[t - off] : 0;
        __syncthreads();
        ps[t] += x;
        __syncthreads();
    }
    const int pairbase = (t == 0) ? 0 : ps[t - 1];
    lstart[2 * t]     = pairbase;
    lstart[2 * t + 1] = pairbase + a0;
    cur[2 * t]        = pairbase;
    cur[2 * t + 1]    = pairbase + a0;
    // Phase 2b: reserve global chunks.
    if (a0) gbase[2 * t]     = atomicAdd(&cursor[2 * t], a0);
    if (a1) gbase[2 * t + 1] = atomicAdd(&cursor[2 * t + 1], a1);
    __syncthreads();

    // Phase 3: scatter into LDS staging, grouped by bucket.
    const int4*   s4 = reinterpret_cast<const int4*>(ei + n_edges + c0);
    const float4* w4 = reinterpret_cast<const float4*>(ew + c0);
    for (int i = t; i < nv; i += 512) {
        const int4 d = d4[i];
        const int4 s = s4[i];
        const float4 w = w4[i];
        const int dd[4] = {d.x, d.y, d.z, d.w};
        const int ss[4] = {s.x, s.y, s.z, s.w};
        const float ww[4] = {w.x, w.y, w.z, w.w};
#pragma unroll
        for (int u = 0; u < 4; ++u) {
            const int b = dd[u] >> LG_NPB;
            const int pos = atomicAdd(&cur[b], 1);
            stg[pos]  = make_int2((ss[u] << LG_NPB) | (dd[u] & (NPB - 1)),
                                  __float_as_int(ww[u]));
            sbkt[pos] = (unsigned short)b;
        }
    }
    for (int i = c0 + (nv << 2) + t; i < c1; i += 512) {
        const int d = ei[i];
        const int s = ei[n_edges + i];
        const int b = d >> LG_NPB;
        const int pos = atomicAdd(&cur[b], 1);
        stg[pos]  = make_int2((s << LG_NPB) | (d & (NPB - 1)),
                              __float_as_int(ew[i]));
        sbkt[pos] = (unsigned short)b;
    }
    __syncthreads();

    // Phase 4: bucket-contiguous write-out.
    for (int i = t; i < cnt; i += 512) {
        const int b = sbkt[i];
        elistA[gbase[b] + (i - lstart[b])] = stg[i];
    }
}

// ---------------------------------------------------------------------------
// Merged sort+pull: one block per bucket. Counting-sort edges into LDS
// (smeta.x holds src byte-offset = src*128), then 8 waves x 16 nodes pull
// with 8-deep gather pipeline, register accumulation, fused ReLU.
// ---------------------------------------------------------------------------
__global__ void __launch_bounds__(512) gnn_sortpull_kernel(
    const __hip_bfloat16* __restrict__ support, const int2* __restrict__ elistA,
    const int* __restrict__ starts, const int* __restrict__ gcounts,
    float* __restrict__ out, int n_nodes) {
    __shared__ int2 smeta[SORT_CAP];      // 32 KB sorted (src_byteoff, w) list
    __shared__ int hist[NPB];
    __shared__ int pfx[NPB];
    __shared__ int segs[NPB + 1];
    __shared__ int cur[NPB];
    const int t = threadIdx.x;
    const int b = blockIdx.x;
    const int bstart = starts[b];
    const int cnt    = min(gcounts[b], SORT_CAP);

    if (t < NPB) hist[t] = 0;
    __syncthreads();
    for (int i = t; i < cnt; i += 512)
        atomicAdd(&hist[elistA[bstart + i].x & (NPB - 1)], 1);
    __syncthreads();

    if (t < NPB) pfx[t] = hist[t];
    __syncthreads();
    for (int off = 1; off < NPB; off <<= 1) {
        int x = 0;
        if (t < NPB && t >= off) x = pfx[t - off];
        __syncthreads();
        if (t < NPB) pfx[t] += x;
        __syncthreads();
    }
    if (t < NPB) {
        const int st = pfx[t] - hist[t];   // exclusive
        segs[t] = st;
        cur[t]  = st;
    }
    if (t == 0) segs[NPB] = cnt;
    __syncthreads();

    for (int i = t; i < cnt; i += 512) {
        const int2 m = elistA[bstart + i];
        const int dlo = m.x & (NPB - 1);
        const int pos = atomicAdd(&cur[dlo], 1);
        smeta[pos] = make_int2(m.x & ~(NPB - 1), m.y);   // src*128 byte offset
    }
    __syncthreads();

    const char* sp = reinterpret_cast<const char*>(support);
    const int lane = t & 63;
    const int wave = t >> 6;              // 0..7
    for (int n = wave; n < NPB; n += 8) {
        const int node = b * NPB + n;
        if (node >= n_nodes) break;
        int e  = segs[n];
        const int e1 = segs[n + 1];
        float acc = 0.f;
        for (; e + 8 <= e1; e += 8) {
            int2 m[8];
#pragma unroll
            for (int u = 0; u < 8; ++u) m[u] = smeta[e + u];
            float g[8];
#pragma unroll
            for (int u = 0; u < 8; ++u)
                g[u] = __bfloat162float(
                    *reinterpret_cast<const __hip_bfloat16*>(sp + m[u].x + lane * 2));
#pragma unroll
            for (int u = 0; u < 8; ++u)
                acc = fmaf(__int_as_float(m[u].y), g[u], acc);
        }
        for (; e + 2 <= e1; e += 2) {
            const int2 m0 = smeta[e];
            const int2 m1 = smeta[e + 1];
            const float g0 = __bfloat162float(
                *reinterpret_cast<const __hip_bfloat16*>(sp + m0.x + lane * 2));
            const float g1 = __bfloat162float(
                *reinterpret_cast<const __hip_bfloat16*>(sp + m1.x + lane * 2));
            acc = fmaf(__int_as_float(m0.y), g0, acc);
            acc = fmaf(__int_as_float(m1.y), g1, acc);
        }
        if (e < e1) {
            const int2 m0 = smeta[e];
            acc = fmaf(__int_as_float(m0.y),
                       __bfloat162float(
                           *reinterpret_cast<const __hip_bfloat16*>(sp + m0.x + lane * 2)),
                       acc);
        }
        out[(size_t)node * F_OUT + lane] = fmaxf(acc, 0.f);
    }
}

extern "C" void kernel_launch(void* const* d_in, const int* in_sizes, int n_in,
                              void* d_out, int out_size, void* d_ws, size_t ws_size,
                              hipStream_t stream) {
    const float* X  = (const float*)d_in[0];   // [N,128] fp32
    const float* W  = (const float*)d_in[1];   // [128,64] fp32
    const int*   EI = (const int*)d_in[2];     // [2,E] int32
    const float* EW = (const float*)d_in[3];   // [E] fp32
    float*       out = (float*)d_out;          // [N,64] fp32

    const int n_edges   = in_sizes[2] / 2;     // 1,600,000
    const int n_rows    = in_sizes[0] / F_IN;  // 100,000
    const int n_nodes   = out_size / F_OUT;    // 100,000
    const int n_buckets = (n_nodes + NPB - 1) >> LG_NPB;  // 782

    // Workspace (~25.7 MB)
    char* ws = (char*)d_ws;
    __hip_bfloat16* support = (__hip_bfloat16*)ws;             // 12.8 MB
    size_t off = (size_t)n_rows * F_OUT * sizeof(__hip_bfloat16);
    int2* elistA = (int2*)(ws + off); off += (size_t)n_edges * sizeof(int2);  // 12.8 MB
    int* gcounts = (int*)(ws + off);  off += MAXB * sizeof(int);
    int* starts  = (int*)(ws + off);  off += MAXB * sizeof(int);
    int* cursor  = (int*)(ws + off);

    hipMemsetAsync(gcounts, 0, (size_t)n_buckets * sizeof(int), stream);

    const int place_blocks = (n_edges + PLACE_CHUNK - 1) / PLACE_CHUNK;  // 400

    gnn_bhist_kernel<<<BIN_BLOCKS, BIN_THREADS, 0, stream>>>(EI, gcounts, n_edges, n_buckets);
    gnn_bscan_kernel<<<1, 1024, 0, stream>>>(gcounts, starts, cursor, n_buckets);
    gnn_place_kernel<<<place_blocks, 512, 0, stream>>>(EI, EW, cursor, elistA, n_edges, n_buckets);
    gnn_gemm_kernel<<<512, 256, 0, stream>>>(X, W, support, n_rows);
    gnn_sortpull_kernel<<<n_buckets, 512, 0, stream>>>(support, elistA, starts, gcounts, out, n_nodes);
}